// Round 3
// baseline (4278.376 us; speedup 1.0000x reference)
//
#include <hip/hip_runtime.h>
#include <hip/hip_bf16.h>
#include <stdint.h>

#define Dm 1024
#define MT 32768
#define NLAYER 6

typedef __attribute__((ext_vector_type(8))) short bfvec8;
typedef __attribute__((ext_vector_type(4))) float fvec4;

__device__ __forceinline__ float bf2f(unsigned short u){
    union { unsigned int i; float f; } v; v.i = ((unsigned int)u) << 16; return v.f;
}
__device__ __forceinline__ unsigned short f2bf(float f){
    union { float f; unsigned int i; } v; v.f = f;
    unsigned int x = v.i;
    return (unsigned short)((x + 0x7fffu + ((x >> 16) & 1u)) >> 16);
}

__device__ __forceinline__ void gload_lds16(const void* g, void* lds){
    __builtin_amdgcn_global_load_lds(
        (const __attribute__((address_space(1))) void*)(uintptr_t)g,
        (__attribute__((address_space(3))) void*)(unsigned int)(uintptr_t)lds,
        16, 0, 0);
}

// ---- W' = dequant(q, scale) + lb @ la  (LoRA folded into the weight), bf16 out.
__global__ __launch_bounds__(256) void prep_w2(const int* __restrict__ q,
                                               const float* __restrict__ sc,
                                               const float* __restrict__ la,
                                               const float* __restrict__ lb,
                                               unsigned short* __restrict__ wbf){
    __shared__ float lbs[256];                  // lb[og..og+7][0..31]
    const int tid = threadIdx.x;
    const int l  = blockIdx.x >> 7;             // 128 blocks per layer
    const int og = (blockIdx.x & 127) * 8;
    lbs[tid] = lb[(size_t)l * Dm * 32 + og * 32 + tid];
    __syncthreads();
    const int k0 = tid * 4;
    float acc[8][4] = {};
    const float* lal = la + (size_t)l * 32 * Dm + k0;
    #pragma unroll 4
    for (int r = 0; r < 32; r++) {
        float4 v = *(const float4*)(lal + (size_t)r * Dm);
        #pragma unroll
        for (int i = 0; i < 8; i++) {
            float c = lbs[i * 32 + r];
            acc[i][0] = fmaf(c, v.x, acc[i][0]);
            acc[i][1] = fmaf(c, v.y, acc[i][1]);
            acc[i][2] = fmaf(c, v.z, acc[i][2]);
            acc[i][3] = fmaf(c, v.w, acc[i][3]);
        }
    }
    #pragma unroll
    for (int i = 0; i < 8; i++) {
        const size_t row = (size_t)l * Dm + og + i;
        int4 qv = *(const int4*)(q + row * Dm + k0);
        float s  = sc[row * (Dm / 16) + (k0 >> 4)];
        float si = s * (1.0f / 7.5f);
        ushort4 o;
        o.x = f2bf(fmaf((float)qv.x, si, acc[i][0] - s));
        o.y = f2bf(fmaf((float)qv.y, si, acc[i][1] - s));
        o.z = f2bf(fmaf((float)qv.z, si, acc[i][2] - s));
        o.w = f2bf(fmaf((float)qv.w, si, acc[i][3] - s));
        *(ushort4*)(wbf + row * Dm + k0) = o;
    }
}

// ---- fp32 -> bf16 convert (n multiple of 1024)
__global__ __launch_bounds__(256) void conv_bf16_kernel(const float* __restrict__ in,
                                                        unsigned short* __restrict__ out){
    size_t i = ((size_t)blockIdx.x * 256 + threadIdx.x) * 4;
    float4 v = *(const float4*)(in + i);
    ushort4 o;
    o.x = f2bf(v.x); o.y = f2bf(v.y); o.z = f2bf(v.z); o.w = f2bf(v.w);
    *(ushort4*)(out + i) = o;
}

// ---- main GEMM: C[m,n] = sum_k A[m,k]*W[n,k] + bias[n] (+bf16 resid)
// 256x256 tile, BK=32, 64 KB LDS dbuf -> 2 blocks/CU (cross-block stall filling).
// One fused phase per K-tile:
//   vmcnt(4)+barrier (tile t landed chip-wide) -> 12 ds_read_b128 ->
//   lgkmcnt(0)+sched_barrier -> 32 MFMA (setprio) -> barrier (buf free) ->
//   stage tile t+2 (4 global_load_lds passes). 8 loads in flight steady-state.
// LDS layout: row-pair interleave (128B line = 2 rows x 4 granules of 16B),
// granule XOR'd by rowpair&7; staging pre-swizzles the GLOBAL source so the
// linear global_load_lds dest matches (both-sides swizzle).
// Epilogue: operands swapped (mfma(W,A)) so D rows index n -> each lane holds
// 4 consecutive n => direct float4/ushort4 stores, no LDS transpose/barriers.
__global__ __launch_bounds__(512, 4) void qlora_gemm(
    const unsigned short* __restrict__ A,
    const unsigned short* __restrict__ W,
    const float* __restrict__ bias,
    const unsigned short* __restrict__ resid,
    float* __restrict__ outf,
    unsigned short* __restrict__ outb)
{
    __shared__ char smem[65536];
    unsigned short* S = (unsigned short*)smem;  // A: [2][8192], B: 16384 + [2][8192]

    const int tid = threadIdx.x;
    const int wave = tid >> 6, lane = tid & 63;
    const int quad = lane >> 4, l16 = lane & 15;
    const int wm = wave >> 2, wn = wave & 3;    // 2m x 4n wave grid, per-wave 128x64

    // bijective XCD swizzle (512 blocks % 8 == 0)
    const int wg = (blockIdx.x & 7) * 64 + (blockIdx.x >> 3);
    const int m0 = (wg >> 2) * 256;
    const int n0 = (wg & 3) * 256;

    // per-thread LDS read offset (ushort units): rowpair-low * 64 + s' * 8
    const int sprime = (((l16 & 1) * 4 + quad) ^ (l16 >> 1));
    const int th_rd = (l16 >> 1) * 64 + sprime * 8;

    // staging source pre-swizzle: LDS slot (rp = tid>>3, s = tid&7) holds
    // data (row = 2*rp + (g>>2), kgran = g&3) with g = s ^ (rp&7)
    const int g = (tid & 7) ^ ((tid >> 3) & 7);
    const int srow = 2 * (tid >> 3) + (g >> 2);   // 0..127 within a pass
    const int skoff = (g & 3) * 8;

    auto stage_tile = [&](int buf, int kt){
        gload_lds16(A + (size_t)(m0 +   0 + srow) * Dm + kt + skoff,
                    smem + buf * 16384 +    0 + tid * 16);
        gload_lds16(A + (size_t)(m0 + 128 + srow) * Dm + kt + skoff,
                    smem + buf * 16384 + 8192 + tid * 16);
        gload_lds16(W + (size_t)(n0 +   0 + srow) * Dm + kt + skoff,
                    smem + 32768 + buf * 16384 +    0 + tid * 16);
        gload_lds16(W + (size_t)(n0 + 128 + srow) * Dm + kt + skoff,
                    smem + 32768 + buf * 16384 + 8192 + tid * 16);
    };

    fvec4 acc[8][4] = {};   // [pm*4+i][ni]

    stage_tile(0, 0);
    stage_tile(1, 32);

    #pragma unroll 2
    for (int t = 0; t < 32; ++t) {
        const int buf = t & 1;
        if (t == 31) asm volatile("s_waitcnt vmcnt(0)" ::: "memory");
        else         asm volatile("s_waitcnt vmcnt(4)" ::: "memory");
        asm volatile("s_barrier" ::: "memory");   // tile t landed for ALL waves

        const unsigned short* Ab = S + buf * 8192;
        const unsigned short* Bb = S + 16384 + buf * 8192;
        bfvec8 b[4], a0[4], a1[4];
        #pragma unroll
        for (int n = 0; n < 4; ++n) b[n]  = *(const bfvec8*)(Bb + (wn * 32 + n * 8) * 64 + th_rd);
        #pragma unroll
        for (int i = 0; i < 4; ++i) a0[i] = *(const bfvec8*)(Ab + (wm * 64 + i * 8) * 64 + th_rd);
        #pragma unroll
        for (int i = 0; i < 4; ++i) a1[i] = *(const bfvec8*)(Ab + (wm * 64 + 32 + i * 8) * 64 + th_rd);
        asm volatile("s_waitcnt lgkmcnt(0)" ::: "memory");
        __builtin_amdgcn_sched_barrier(0);        // rule #18: pin MFMA after lgkm0

        __builtin_amdgcn_s_setprio(1);
        #pragma unroll
        for (int i = 0; i < 4; ++i)
            #pragma unroll
            for (int n = 0; n < 4; ++n)
                acc[i][n] = __builtin_amdgcn_mfma_f32_16x16x32_bf16(b[n], a0[i], acc[i][n], 0, 0, 0);
        #pragma unroll
        for (int i = 0; i < 4; ++i)
            #pragma unroll
            for (int n = 0; n < 4; ++n)
                acc[4 + i][n] = __builtin_amdgcn_mfma_f32_16x16x32_bf16(b[n], a1[i], acc[4 + i][n], 0, 0, 0);
        __builtin_amdgcn_s_setprio(0);

        asm volatile("s_barrier" ::: "memory");   // all waves' reads of buf done
        if (t < 30) stage_tile(buf, (t + 2) * 32);
    }

    // ---- epilogue: direct stores. D (swapped) => lane holds m = ...+l16,
    // n = ...+quad*4+{0..3} (4 consecutive n per fragment = float4).
    float4 b4[4];
    #pragma unroll
    for (int n = 0; n < 4; ++n)
        b4[n] = *(const float4*)(bias + n0 + wn * 64 + n * 16 + quad * 4);
    #pragma unroll
    for (int a = 0; a < 8; ++a) {
        const int m = m0 + wm * 128 + (a >> 2) * 64 + (a & 3) * 16 + l16;
        #pragma unroll
        for (int n = 0; n < 4; ++n) {
            const size_t off = (size_t)m * Dm + n0 + wn * 64 + n * 16 + quad * 4;
            float4 v;
            v.x = acc[a][n][0] + b4[n].x;
            v.y = acc[a][n][1] + b4[n].y;
            v.z = acc[a][n][2] + b4[n].z;
            v.w = acc[a][n][3] + b4[n].w;
            if (resid) {
                ushort4 rv = *(const ushort4*)(resid + off);
                v.x += bf2f(rv.x); v.y += bf2f(rv.y);
                v.z += bf2f(rv.z); v.w += bf2f(rv.w);
            }
            if (outf) *(float4*)(outf + off) = v;
            if (outb) {
                ushort4 o;
                o.x = f2bf(v.x); o.y = f2bf(v.y); o.z = f2bf(v.z); o.w = f2bf(v.w);
                *(ushort4*)(outb + off) = o;
            }
        }
    }
}

// ---- fast exact GELU: erf via Abramowitz-Stegun 7.1.26 (|err| <= 1.5e-7)
__device__ __forceinline__ float gelu_exact(float z){
    float a = fabsf(z) * 0.70710678118654752f;
    float t = 1.0f / fmaf(0.3275911f, a, 1.0f);
    float p = t * fmaf(t, fmaf(t, fmaf(t, fmaf(t, 1.061405429f, -1.453152027f),
                                       1.421413741f), -0.284496736f), 0.254829592f);
    float e = __expf(-a * a);
    float erfa = copysignf(fmaf(-p, e, 1.0f), z);
    return 0.5f * z * (1.0f + erfa);
}

// ---- LayerNorm + GELU over rows of 1024, one block per row
__global__ __launch_bounds__(256) void ln_gelu_kernel(const unsigned short* __restrict__ Y,
                                                      const float* __restrict__ g,
                                                      const float* __restrict__ b,
                                                      unsigned short* __restrict__ Aout){
    const int row = blockIdx.x;
    const int tid = threadIdx.x;
    const unsigned short* yr = Y + (size_t)row * Dm;
    ushort4 u = *(const ushort4*)(yr + tid * 4);
    float x0 = bf2f(u.x), x1 = bf2f(u.y), x2 = bf2f(u.z), x3 = bf2f(u.w);
    float s  = x0 + x1 + x2 + x3;
    float ss = x0 * x0 + x1 * x1 + x2 * x2 + x3 * x3;
    #pragma unroll
    for (int d = 32; d > 0; d >>= 1) {
        s  += __shfl_down(s, d);
        ss += __shfl_down(ss, d);
    }
    __shared__ float sb[8];
    const int wave = tid >> 6, lane = tid & 63;
    if (lane == 0) { sb[wave] = s; sb[4 + wave] = ss; }
    __syncthreads();
    s  = sb[0] + sb[1] + sb[2] + sb[3];
    ss = sb[4] + sb[5] + sb[6] + sb[7];
    const float mu = s * (1.0f / Dm);
    const float var = ss * (1.0f / Dm) - mu * mu;
    const float rstd = rsqrtf(var + 1e-5f);
    float4 gv = *(const float4*)(g + tid * 4);
    float4 bv = *(const float4*)(b + tid * 4);
    float z0 = (x0 - mu) * rstd * gv.x + bv.x;
    float z1 = (x1 - mu) * rstd * gv.y + bv.y;
    float z2 = (x2 - mu) * rstd * gv.z + bv.z;
    float z3 = (x3 - mu) * rstd * gv.w + bv.w;
    ushort4 o;
    o.x = f2bf(gelu_exact(z0)); o.y = f2bf(gelu_exact(z1));
    o.z = f2bf(gelu_exact(z2)); o.w = f2bf(gelu_exact(z3));
    *(ushort4*)(Aout + (size_t)row * Dm + tid * 4) = o;
}

extern "C" void kernel_launch(void* const* d_in, const int* in_sizes, int n_in,
                              void* d_out, int out_size, void* d_ws, size_t ws_size,
                              hipStream_t stream) {
    (void)in_sizes; (void)n_in; (void)out_size; (void)ws_size;
    const float* x   = (const float*)d_in[0];
    const int*   qw  = (const int*)d_in[1];
    const float* sc  = (const float*)d_in[2];
    const float* bia = (const float*)d_in[3];
    const float* la  = (const float*)d_in[4];
    const float* lb  = (const float*)d_in[5];
    const float* gam = (const float*)d_in[6];
    const float* bet = (const float*)d_in[7];
    float* out = (float*)d_out;

    char* p = (char*)d_ws;
    unsigned short* Wbf = (unsigned short*)p; p += (size_t)NLAYER * Dm * Dm * 2;
    unsigned short* Hb  = (unsigned short*)p; p += (size_t)MT * Dm * 2;  // residual stream (bf16)
    unsigned short* Gb  = (unsigned short*)p; p += (size_t)MT * Dm * 2;  // GEMM1 out
    unsigned short* Pb  = (unsigned short*)p; p += (size_t)MT * Dm * 2;  // ln_gelu out

    prep_w2<<<NLAYER * Dm / 8, 256, 0, stream>>>(qw, sc, la, lb, Wbf);
    conv_bf16_kernel<<<MT * (Dm / 4) / 256, 256, 0, stream>>>(x, Hb);

    for (int blk = 0; blk < 3; blk++) {
        int i0 = 2 * blk, i1 = i0 + 1;
        qlora_gemm<<<512, 512, 0, stream>>>(
            Hb, Wbf + (size_t)i0 * Dm * Dm,
            bia + i0 * Dm, nullptr, nullptr, Gb);
        ln_gelu_kernel<<<MT, 256, 0, stream>>>(Gb, gam + blk * Dm, bet + blk * Dm, Pb);
        qlora_gemm<<<512, 512, 0, stream>>>(
            Pb, Wbf + (size_t)i1 * Dm * Dm,
            bia + i1 * Dm, Hb,
            blk == 2 ? out : nullptr,
            blk == 2 ? nullptr : Hb);
    }
}

// Round 4
// 893.205 us; speedup vs baseline: 4.7899x; 4.7899x over previous
//
#include <hip/hip_runtime.h>
#include <hip/hip_bf16.h>
#include <stdint.h>

#define Dm 1024
#define MT 32768
#define NLAYER 6

typedef __attribute__((ext_vector_type(8))) short bfvec8;
typedef __attribute__((ext_vector_type(4))) float fvec4;

__device__ __forceinline__ float bf2f(unsigned short u){
    union { unsigned int i; float f; } v; v.i = ((unsigned int)u) << 16; return v.f;
}
__device__ __forceinline__ unsigned short f2bf(float f){
    union { float f; unsigned int i; } v; v.f = f;
    unsigned int x = v.i;
    return (unsigned short)((x + 0x7fffu + ((x >> 16) & 1u)) >> 16);
}

__device__ __forceinline__ void gload_lds16(const void* g, void* lds){
    __builtin_amdgcn_global_load_lds(
        (const __attribute__((address_space(1))) void*)(uintptr_t)g,
        (__attribute__((address_space(3))) void*)(unsigned int)(uintptr_t)lds,
        16, 0, 0);
}

// ---- W' = dequant(q, scale) + lb @ la  (LoRA folded into the weight), bf16 out.
__global__ __launch_bounds__(256) void prep_w2(const int* __restrict__ q,
                                               const float* __restrict__ sc,
                                               const float* __restrict__ la,
                                               const float* __restrict__ lb,
                                               unsigned short* __restrict__ wbf){
    __shared__ float lbs[256];                  // lb[og..og+7][0..31]
    const int tid = threadIdx.x;
    const int l  = blockIdx.x >> 7;             // 128 blocks per layer
    const int og = (blockIdx.x & 127) * 8;
    lbs[tid] = lb[(size_t)l * Dm * 32 + og * 32 + tid];
    __syncthreads();
    const int k0 = tid * 4;
    float acc[8][4] = {};
    const float* lal = la + (size_t)l * 32 * Dm + k0;
    #pragma unroll 4
    for (int r = 0; r < 32; r++) {
        float4 v = *(const float4*)(lal + (size_t)r * Dm);
        #pragma unroll
        for (int i = 0; i < 8; i++) {
            float c = lbs[i * 32 + r];
            acc[i][0] = fmaf(c, v.x, acc[i][0]);
            acc[i][1] = fmaf(c, v.y, acc[i][1]);
            acc[i][2] = fmaf(c, v.z, acc[i][2]);
            acc[i][3] = fmaf(c, v.w, acc[i][3]);
        }
    }
    #pragma unroll
    for (int i = 0; i < 8; i++) {
        const size_t row = (size_t)l * Dm + og + i;
        int4 qv = *(const int4*)(q + row * Dm + k0);
        float s  = sc[row * (Dm / 16) + (k0 >> 4)];
        float si = s * (1.0f / 7.5f);
        ushort4 o;
        o.x = f2bf(fmaf((float)qv.x, si, acc[i][0] - s));
        o.y = f2bf(fmaf((float)qv.y, si, acc[i][1] - s));
        o.z = f2bf(fmaf((float)qv.z, si, acc[i][2] - s));
        o.w = f2bf(fmaf((float)qv.w, si, acc[i][3] - s));
        *(ushort4*)(wbf + row * Dm + k0) = o;
    }
}

// ---- fp32 -> bf16 convert (n multiple of 1024)
__global__ __launch_bounds__(256) void conv_bf16_kernel(const float* __restrict__ in,
                                                        unsigned short* __restrict__ out){
    size_t i = ((size_t)blockIdx.x * 256 + threadIdx.x) * 4;
    float4 v = *(const float4*)(in + i);
    ushort4 o;
    o.x = f2bf(v.x); o.y = f2bf(v.y); o.z = f2bf(v.z); o.w = f2bf(v.w);
    *(ushort4*)(out + i) = o;
}

// ---- main GEMM: C[m,n] = sum_k A[m,k]*W[n,k] + bias[n] (+bf16 resid)
// 128x256 tile, 256 thr (4 waves 1m x 4n, per-wave 128x64), BK=32,
// TRIPLE-buffered LDS (A 3x8KB + B 3x16KB = 72 KB) -> 2 blocks/CU
// (LDS 144<=160; VGPR ~205 <= 256 cap from __launch_bounds__(256,2)).
// Per K-tile phase: vmcnt(12)+barrier (tile t landed) -> 12 ds_read_b128 ->
// lgkmcnt(0)+sched_barrier -> 32 MFMA (setprio) -> barrier -> stage t+3.
// 18 loads in flight steady; counted drain gives 3 phases of flight, and the
// sibling block on the CU fills the residual latency (m114 overlap).
// LDS layout: round-3's verified rowpair interleave (bank-conflict-free,
// SQ_LDS_BANK_CONFLICT=0): slot s of rowpair rp holds g = s ^ (rp&7),
// data (row = 2rp + (g>>2), kgran = g&3); staging pre-swizzles the GLOBAL
// source so the linear global_load_lds dest matches (both-sides, rule #21).
// Epilogue: swapped mfma(W,A) -> lane holds 4 consecutive n => direct
// float4/ushort4 stores, no LDS transpose, no epilogue barriers.
__global__ __launch_bounds__(256, 2) void qlora_gemm(
    const unsigned short* __restrict__ A,
    const unsigned short* __restrict__ W,
    const float* __restrict__ bias,
    const unsigned short* __restrict__ resid,
    float* __restrict__ outf,
    unsigned short* __restrict__ outb)
{
    __shared__ char smem[73728];                // A: 3x8192 B, B: 24576 + 3x16384 B
    unsigned short* S = (unsigned short*)smem;

    const int tid = threadIdx.x;
    const int wave = tid >> 6, lane = tid & 63;
    const int quad = lane >> 4, l16 = lane & 15;

    // bijective XCD swizzle (1024 blocks % 8 == 0): XCD x gets m-tiles
    // x*32..x*32+31, all 4 n-tiles consecutive -> A-band L2 reuse per XCD.
    const int wg = (blockIdx.x & 7) * 128 + (blockIdx.x >> 3);
    const int m0 = (wg >> 2) * 128;
    const int n0 = (wg & 3) * 256;

    // per-thread LDS read offset (ushort units) within a 16-row block
    const int th_rd = (l16 >> 1) * 64 + ((((l16 & 1) * 4 + quad) ^ (l16 >> 1)) * 8);

    // staging source pre-swizzle: slot (rp=tid>>3, s=tid&7) holds
    // (row = 2rp + (g>>2), kgran = g&3), g = s ^ (rp&7)
    const int g = (tid & 7) ^ ((tid >> 3) & 7);
    const int srow = 2 * (tid >> 3) + (g >> 2);   // 0..63 within a pass
    const int skoff = (g & 3) * 8;

    // one pass = 64 rows x 32 K (256 thr x 16 B = 4 KB). A: 2 passes, B: 4.
    auto stage_tile = [&](int buf, int kt){
        char* Ad = smem + buf * 8192;
        char* Bd = smem + 24576 + buf * 16384;
        gload_lds16(A + (size_t)(m0 +  0 + srow) * Dm + kt + skoff, Ad + 0    + tid * 16);
        gload_lds16(A + (size_t)(m0 + 64 + srow) * Dm + kt + skoff, Ad + 4096 + tid * 16);
        #pragma unroll
        for (int p = 0; p < 4; ++p)
            gload_lds16(W + (size_t)(n0 + p * 64 + srow) * Dm + kt + skoff,
                        Bd + p * 4096 + tid * 16);
    };

    fvec4 acc[8][4] = {};   // [mi][ni]; per-wave 128x64 output

    stage_tile(0, 0);
    stage_tile(1, 32);
    stage_tile(2, 64);

    int bufo = 0;
    #pragma unroll 1
    for (int t = 0; t < 32; ++t) {
        if (t < 30)      asm volatile("s_waitcnt vmcnt(12)" ::: "memory");
        else if (t == 30) asm volatile("s_waitcnt vmcnt(6)"  ::: "memory");
        else              asm volatile("s_waitcnt vmcnt(0)"  ::: "memory");
        asm volatile("s_barrier" ::: "memory");   // tile t landed for all waves

        const unsigned short* Ab = S + bufo * 4096;            // ushort units
        const unsigned short* Bb = S + 12288 + bufo * 8192;
        bfvec8 b[4], a[8];
        #pragma unroll
        for (int n = 0; n < 4; ++n) b[n] = *(const bfvec8*)(Bb + wave * 2048 + n * 512 + th_rd);
        #pragma unroll
        for (int i = 0; i < 8; ++i) a[i] = *(const bfvec8*)(Ab + i * 512 + th_rd);
        asm volatile("s_waitcnt lgkmcnt(0)" ::: "memory");
        __builtin_amdgcn_sched_barrier(0);        // rule #18: pin MFMA after lgkm0

        __builtin_amdgcn_s_setprio(1);
        #pragma unroll
        for (int i = 0; i < 8; ++i)
            #pragma unroll
            for (int n = 0; n < 4; ++n)
                acc[i][n] = __builtin_amdgcn_mfma_f32_16x16x32_bf16(b[n], a[i], acc[i][n], 0, 0, 0);
        __builtin_amdgcn_s_setprio(0);

        asm volatile("s_barrier" ::: "memory");   // all waves' reads of buf done
        if (t < 29) stage_tile(bufo, (t + 3) * 32);
        bufo = (bufo == 2) ? 0 : bufo + 1;
    }

    // ---- epilogue: direct stores. Swapped mfma => lane holds m = mi*16+l16,
    // n = wave*64 + ni*16 + quad*4 + {0..3} (consecutive => float4).
    float4 b4[4];
    #pragma unroll
    for (int n = 0; n < 4; ++n)
        b4[n] = *(const float4*)(bias + n0 + wave * 64 + n * 16 + quad * 4);
    #pragma unroll
    for (int i = 0; i < 8; ++i) {
        const int m = m0 + i * 16 + l16;
        #pragma unroll
        for (int n = 0; n < 4; ++n) {
            const size_t off = (size_t)m * Dm + n0 + wave * 64 + n * 16 + quad * 4;
            float4 v;
            v.x = acc[i][n][0] + b4[n].x;
            v.y = acc[i][n][1] + b4[n].y;
            v.z = acc[i][n][2] + b4[n].z;
            v.w = acc[i][n][3] + b4[n].w;
            if (resid) {
                ushort4 rv = *(const ushort4*)(resid + off);
                v.x += bf2f(rv.x); v.y += bf2f(rv.y);
                v.z += bf2f(rv.z); v.w += bf2f(rv.w);
            }
            if (outf) *(float4*)(outf + off) = v;
            if (outb) {
                ushort4 o;
                o.x = f2bf(v.x); o.y = f2bf(v.y); o.z = f2bf(v.z); o.w = f2bf(v.w);
                *(ushort4*)(outb + off) = o;
            }
        }
    }
}

// ---- fast exact GELU: erf via Abramowitz-Stegun 7.1.26 (|err| <= 1.5e-7)
__device__ __forceinline__ float gelu_exact(float z){
    float a = fabsf(z) * 0.70710678118654752f;
    float t = 1.0f / fmaf(0.3275911f, a, 1.0f);
    float p = t * fmaf(t, fmaf(t, fmaf(t, fmaf(t, 1.061405429f, -1.453152027f),
                                       1.421413741f), -0.284496736f), 0.254829592f);
    float e = __expf(-a * a);
    float erfa = copysignf(fmaf(-p, e, 1.0f), z);
    return 0.5f * z * (1.0f + erfa);
}

// ---- LayerNorm + GELU over rows of 1024, one block per row
__global__ __launch_bounds__(256) void ln_gelu_kernel(const unsigned short* __restrict__ Y,
                                                      const float* __restrict__ g,
                                                      const float* __restrict__ b,
                                                      unsigned short* __restrict__ Aout){
    const int row = blockIdx.x;
    const int tid = threadIdx.x;
    const unsigned short* yr = Y + (size_t)row * Dm;
    ushort4 u = *(const ushort4*)(yr + tid * 4);
    float x0 = bf2f(u.x), x1 = bf2f(u.y), x2 = bf2f(u.z), x3 = bf2f(u.w);
    float s  = x0 + x1 + x2 + x3;
    float ss = x0 * x0 + x1 * x1 + x2 * x2 + x3 * x3;
    #pragma unroll
    for (int d = 32; d > 0; d >>= 1) {
        s  += __shfl_down(s, d);
        ss += __shfl_down(ss, d);
    }
    __shared__ float sb[8];
    const int wave = tid >> 6, lane = tid & 63;
    if (lane == 0) { sb[wave] = s; sb[4 + wave] = ss; }
    __syncthreads();
    s  = sb[0] + sb[1] + sb[2] + sb[3];
    ss = sb[4] + sb[5] + sb[6] + sb[7];
    const float mu = s * (1.0f / Dm);
    const float var = ss * (1.0f / Dm) - mu * mu;
    const float rstd = rsqrtf(var + 1e-5f);
    float4 gv = *(const float4*)(g + tid * 4);
    float4 bv = *(const float4*)(b + tid * 4);
    float z0 = (x0 - mu) * rstd * gv.x + bv.x;
    float z1 = (x1 - mu) * rstd * gv.y + bv.y;
    float z2 = (x2 - mu) * rstd * gv.z + bv.z;
    float z3 = (x3 - mu) * rstd * gv.w + bv.w;
    ushort4 o;
    o.x = f2bf(gelu_exact(z0)); o.y = f2bf(gelu_exact(z1));
    o.z = f2bf(gelu_exact(z2)); o.w = f2bf(gelu_exact(z3));
    *(ushort4*)(Aout + (size_t)row * Dm + tid * 4) = o;
}

extern "C" void kernel_launch(void* const* d_in, const int* in_sizes, int n_in,
                              void* d_out, int out_size, void* d_ws, size_t ws_size,
                              hipStream_t stream) {
    (void)in_sizes; (void)n_in; (void)out_size; (void)ws_size;
    const float* x   = (const float*)d_in[0];
    const int*   qw  = (const int*)d_in[1];
    const float* sc  = (const float*)d_in[2];
    const float* bia = (const float*)d_in[3];
    const float* la  = (const float*)d_in[4];
    const float* lb  = (const float*)d_in[5];
    const float* gam = (const float*)d_in[6];
    const float* bet = (const float*)d_in[7];
    float* out = (float*)d_out;

    char* p = (char*)d_ws;
    unsigned short* Wbf = (unsigned short*)p; p += (size_t)NLAYER * Dm * Dm * 2;
    unsigned short* Hb  = (unsigned short*)p; p += (size_t)MT * Dm * 2;  // residual stream (bf16)
    unsigned short* Gb  = (unsigned short*)p; p += (size_t)MT * Dm * 2;  // GEMM1 out
    unsigned short* Pb  = (unsigned short*)p; p += (size_t)MT * Dm * 2;  // ln_gelu out

    prep_w2<<<NLAYER * Dm / 8, 256, 0, stream>>>(qw, sc, la, lb, Wbf);
    conv_bf16_kernel<<<MT * (Dm / 4) / 256, 256, 0, stream>>>(x, Hb);

    for (int blk = 0; blk < 3; blk++) {
        int i0 = 2 * blk, i1 = i0 + 1;
        qlora_gemm<<<1024, 256, 0, stream>>>(
            Hb, Wbf + (size_t)i0 * Dm * Dm,
            bia + i0 * Dm, nullptr, nullptr, Gb);
        ln_gelu_kernel<<<MT, 256, 0, stream>>>(Gb, gam + blk * Dm, bet + blk * Dm, Pb);
        qlora_gemm<<<1024, 256, 0, stream>>>(
            Pb, Wbf + (size_t)i1 * Dm * Dm,
            bia + i1 * Dm, Hb,
            blk == 2 ? out : nullptr,
            blk == 2 ? nullptr : Hb);
    }
}